// Round 1
// baseline (4698.412 us; speedup 1.0000x reference)
//
#include <hip/hip_runtime.h>
#include <math.h>

#define NB 64      // batch
#define NP 12      // encoder steps
#define NQ 12      // decoder steps
#define NT 24      // P+Q
#define NN 325     // nodes
#define ND 64      // units
#define CF 128     // 2*D
#define NR 20800   // NN*NB rows

struct Chunks { const float* p[6]; int s[6]; };

__global__ void k_te(const int* __restrict__ TE, const float* __restrict__ W1,
                     const float* __restrict__ b1, const float* __restrict__ W2,
                     const float* __restrict__ b2, float* __restrict__ te) {
  int row = blockIdx.x;            // b*24+t  (1536 rows)
  int d = threadIdx.x;
  __shared__ float s[ND];
  int wd = TE[row * 2 + 0], td = TE[row * 2 + 1];
  float v = W1[wd * ND + d] + W1[(7 + td) * ND + d] + b1[d];
  s[d] = v > 0.f ? v : 0.f;
  __syncthreads();
  float acc = b2[d];
  #pragma unroll 8
  for (int k = 0; k < ND; k++) acc = fmaf(s[k], W2[k * ND + d], acc);
  te[row * ND + d] = acc;
}

__global__ void k_zero(float* __restrict__ p, int n) {
  int i = blockIdx.x * 256 + threadIdx.x;
  if (i < n) p[i] = 0.f;
}

// Build V = [x_t | h] in layout (N, B, 128). Encoder: x_t = embX + te + E_se;
// decoder: x_t = te + E_se.
__global__ void k_buildV(const float* __restrict__ X, const float* __restrict__ te,
                         const float* __restrict__ E_se, const float* __restrict__ Wi1,
                         const float* __restrict__ bi1, const float* __restrict__ Wi2,
                         const float* __restrict__ bi2, const float* __restrict__ h,
                         float* __restrict__ V, int t, int is_enc) {
  int row = blockIdx.x;            // n*64 + b
  int n = row >> 6, b = row & 63;
  int d = threadIdx.x;
  __shared__ float s[ND];
  float acc;
  if (is_enc) {
    float x = X[(b * NP + t) * NN + n];
    float v = fmaf(x, Wi1[d], bi1[d]);
    s[d] = v > 0.f ? v : 0.f;
    __syncthreads();
    acc = bi2[d];
    #pragma unroll 8
    for (int k = 0; k < ND; k++) acc = fmaf(s[k], Wi2[k * ND + d], acc);
    acc += te[(b * NT + t) * ND + d] + E_se[n * ND + d];
  } else {
    acc = te[(b * NT + NP + t) * ND + d] + E_se[n * ND + d];
  }
  V[row * CF + d] = acc;
  V[row * CF + ND + d] = h[row * ND + d];
}

// Dense S-matmul: O = S @ Vin, S (325x325), Vin (325 x C). z=0 -> S0/O0, z=1 -> S1/O1.
template<int C>
__global__ void k_spmm(const float* __restrict__ S0g, const float* __restrict__ S1g,
                       const float* __restrict__ Vin, float* __restrict__ O0,
                       float* __restrict__ O1) {
  const float* S = blockIdx.z ? S1g : S0g;
  float* O = blockIdx.z ? O1 : O0;
  int m0 = blockIdx.y * 32;
  int c0 = blockIdx.x * 128;
  __shared__ float sS[32][17];
  __shared__ float sV[16][128];
  int tid = threadIdx.x;
  int tx = tid & 31, ty = tid >> 5;
  float acc[4][4] = {};
  for (int k0 = 0; k0 < NN; k0 += 16) {
    #pragma unroll
    for (int i = 0; i < 2; i++) {          // S tile: 32x16
      int idx = tid + i * 256;
      int mm = idx >> 4, kk = idx & 15;
      int gm = m0 + mm, gk = k0 + kk;
      sS[mm][kk] = (gm < NN && gk < NN) ? S[gm * NN + gk] : 0.f;
    }
    #pragma unroll
    for (int i = 0; i < 2; i++) {          // V tile: 16x128
      int idx = tid + i * 256;
      int rr = idx >> 5, cq = idx & 31;
      int gk = k0 + rr;
      float4 val = make_float4(0.f, 0.f, 0.f, 0.f);
      if (gk < NN) val = *(const float4*)&Vin[(size_t)gk * C + c0 + cq * 4];
      *(float4*)&sV[rr][cq * 4] = val;
    }
    __syncthreads();
    #pragma unroll
    for (int k = 0; k < 16; k++) {
      float4 bv = *(const float4*)&sV[k][tx * 4];
      #pragma unroll
      for (int j = 0; j < 4; j++) {
        float a = sS[ty * 4 + j][k];
        acc[j][0] = fmaf(a, bv.x, acc[j][0]);
        acc[j][1] = fmaf(a, bv.y, acc[j][1]);
        acc[j][2] = fmaf(a, bv.z, acc[j][2]);
        acc[j][3] = fmaf(a, bv.w, acc[j][3]);
      }
    }
    __syncthreads();
  }
  #pragma unroll
  for (int j = 0; j < 4; j++) {
    int gm = m0 + ty * 4 + j;
    if (gm < NN)
      *(float4*)&O[(size_t)gm * C + c0 + tx * 4] =
          make_float4(acc[j][0], acc[j][1], acc[j][2], acc[j][3]);
  }
}

// (20800 x 384) @ W(384 x NW). A gathered from 6 K-chunks of 64 (ptr+stride each).
// MODE 0 (gate): val=sigmoid(acc+bg); c<64 -> rh = r*h ; c>=64 -> u.
// MODE 1 (cand): c=tanh(acc+bc); h = u*h + (1-u)*c  (in place).
template<int NW, int MODE>
__global__ void k_gemm(Chunks ch, const float* __restrict__ W,
                       const float* __restrict__ bias, float* hbuf,
                       float* rh, float* ubuf) {
  int row0 = blockIdx.y * 64;
  int c0 = blockIdx.x * 64;
  int tid = threadIdx.x;
  int tx = tid & 15, ty = tid >> 4;
  __shared__ float sA[64][20];   // padded; float4 stores stay 16B-aligned (20*4=80)
  __shared__ float sB[16][64];
  float acc[4][4] = {};
  for (int kt = 0; kt < 24; kt++) {        // 384 / 16
    int chunk = kt >> 2;
    int kin = (kt & 3) * 16;
    const float* Ap = ch.p[chunk];
    int As = ch.s[chunk];
    {
      int mm = tid >> 2;
      int kq = (tid & 3) * 4;
      *(float4*)&sA[mm][kq] = *(const float4*)(Ap + (size_t)(row0 + mm) * As + kin + kq);
    }
    {
      int kk = tid >> 4;
      int cq = (tid & 15) * 4;
      *(float4*)&sB[kk][cq] = *(const float4*)&W[(size_t)(kt * 16 + kk) * NW + c0 + cq];
    }
    __syncthreads();
    #pragma unroll
    for (int k = 0; k < 16; k++) {
      float4 bv = *(const float4*)&sB[k][tx * 4];
      #pragma unroll
      for (int j = 0; j < 4; j++) {
        float a = sA[ty * 4 + j][k];
        acc[j][0] = fmaf(a, bv.x, acc[j][0]);
        acc[j][1] = fmaf(a, bv.y, acc[j][1]);
        acc[j][2] = fmaf(a, bv.z, acc[j][2]);
        acc[j][3] = fmaf(a, bv.w, acc[j][3]);
      }
    }
    __syncthreads();
  }
  #pragma unroll
  for (int j = 0; j < 4; j++) {
    int row = row0 + ty * 4 + j;
    #pragma unroll
    for (int i = 0; i < 4; i++) {
      int c = c0 + tx * 4 + i;
      float v = acc[j][i] + bias[c];
      if (MODE == 0) {
        float sg = 1.f / (1.f + __expf(-v));
        if (c < ND) rh[row * ND + c] = sg * hbuf[row * ND + c];
        else        ubuf[row * ND + (c - ND)] = sg;
      } else {
        float cv = tanhf(v);
        float u = ubuf[row * ND + c];
        float hold = hbuf[row * ND + c];
        hbuf[row * ND + c] = u * hold + (1.f - u) * cv;
      }
    }
  }
}

// out[b,q,n] = relu(h[n,b,:] @ W1 + b1) @ W2 + b2
__global__ void k_out(const float* __restrict__ h, const float* __restrict__ W1,
                      const float* __restrict__ b1, const float* __restrict__ W2,
                      const float* __restrict__ b2, float* __restrict__ out, int q) {
  int row = blockIdx.x;            // n*64 + b
  int n = row >> 6, b = row & 63;
  int d = threadIdx.x;
  __shared__ float s[ND];
  s[d] = h[row * ND + d];
  __syncthreads();
  float acc = b1[d];
  #pragma unroll 8
  for (int k = 0; k < ND; k++) acc = fmaf(s[k], W1[k * ND + d], acc);
  acc = acc > 0.f ? acc : 0.f;
  float p = acc * W2[d];
  #pragma unroll
  for (int off = 32; off > 0; off >>= 1) p += __shfl_down(p, off);
  if (d == 0) out[(b * NQ + q) * NN + n] = p + b2[0];
}

extern "C" void kernel_launch(void* const* d_in, const int* in_sizes, int n_in,
                              void* d_out, int out_size, void* d_ws, size_t ws_size,
                              hipStream_t stream) {
  const float* X     = (const float*)d_in[0];
  const int*   TE    = (const int*)  d_in[1];
  const float* S0    = (const float*)d_in[2];
  const float* S1    = (const float*)d_in[3];
  const float* W_te1 = (const float*)d_in[4];
  const float* b_te1 = (const float*)d_in[5];
  const float* W_te2 = (const float*)d_in[6];
  const float* b_te2 = (const float*)d_in[7];
  const float* E_se  = (const float*)d_in[8];
  const float* W_in1 = (const float*)d_in[9];
  const float* b_in1 = (const float*)d_in[10];
  const float* W_in2 = (const float*)d_in[11];
  const float* b_in2 = (const float*)d_in[12];
  const float* enc_Wg = (const float*)d_in[13];
  const float* enc_bg = (const float*)d_in[14];
  const float* enc_Wc = (const float*)d_in[15];
  const float* enc_bc = (const float*)d_in[16];
  const float* dec_Wg = (const float*)d_in[17];
  const float* dec_bg = (const float*)d_in[18];
  const float* dec_Wc = (const float*)d_in[19];
  const float* dec_bc = (const float*)d_in[20];
  const float* W_out1 = (const float*)d_in[21];
  const float* b_out1 = (const float*)d_in[22];
  const float* W_out2 = (const float*)d_in[23];
  const float* b_out2 = (const float*)d_in[24];
  float* out = (float*)d_out;
  float* ws = (float*)d_ws;

  // workspace layout (floats)
  float* te   = ws;                 // 1536*64      =    98304
  float* h    = te   + 98304;       // NR*64        =  1331200
  float* V    = h    + 1331200;     // NR*128       =  2662400
  float* SV0  = V    + 2662400;
  float* SV1  = SV0  + 2662400;
  float* RH   = SV1  + 2662400;     // NR*64
  float* SRH0 = RH   + 1331200;
  float* SRH1 = SRH0 + 1331200;
  float* U    = SRH1 + 1331200;     // total ~56.2 MiB

  k_te<<<NB * NT, ND, 0, stream>>>(TE, W_te1, b_te1, W_te2, b_te2, te);
  k_zero<<<(1331200 + 255) / 256, 256, 0, stream>>>(h, 1331200);

  Chunks gateCh{{V, V + ND, SV0, SV0 + ND, SV1, SV1 + ND}, {CF, CF, CF, CF, CF, CF}};
  Chunks candCh{{V, RH, SV0, SRH0, SV1, SRH1}, {CF, ND, CF, ND, CF, ND}};

  for (int t = 0; t < NT; t++) {
    int enc = (t < NP) ? 1 : 0;
    int tt = enc ? t : t - NP;
    const float* Wg = enc ? enc_Wg : dec_Wg;
    const float* bg = enc ? enc_bg : dec_bg;
    const float* Wc = enc ? enc_Wc : dec_Wc;
    const float* bc = enc ? enc_bc : dec_bc;

    k_buildV<<<NR, ND, 0, stream>>>(X, te, E_se, W_in1, b_in1, W_in2, b_in2, h, V, tt, enc);
    k_spmm<8192><<<dim3(64, 11, 2), 256, 0, stream>>>(S0, S1, V, SV0, SV1);
    k_gemm<128, 0><<<dim3(2, 325), 256, 0, stream>>>(gateCh, Wg, bg, h, RH, U);
    k_spmm<4096><<<dim3(32, 11, 2), 256, 0, stream>>>(S0, S1, RH, SRH0, SRH1);
    k_gemm<64, 1><<<dim3(1, 325), 256, 0, stream>>>(candCh, Wc, bc, h, RH, U);
    if (!enc) k_out<<<NR, ND, 0, stream>>>(h, W_out1, b_out1, W_out2, b_out2, out, tt);
  }
}

// Round 2
// 2986.988 us; speedup vs baseline: 1.5730x; 1.5730x over previous
//
#include <hip/hip_runtime.h>
#include <math.h>

#define NB 64      // batch
#define NP 12      // encoder steps
#define NQ 12      // decoder steps
#define NT 24      // P+Q
#define NN 325     // nodes
#define ND 64      // units
#define CF 128     // 2*D
#define NR 20800   // NN*NB rows
#define CAP 64     // max nnz per S row (mean ~20.5, 10 sigma < 64)

struct Chunks { const float* p[6]; int s[6]; };

__global__ void k_te(const int* __restrict__ TE, const float* __restrict__ W1,
                     const float* __restrict__ b1, const float* __restrict__ W2,
                     const float* __restrict__ b2, float* __restrict__ te) {
  int row = blockIdx.x;            // b*24+t  (1536 rows)
  int d = threadIdx.x;
  __shared__ float s[ND];
  int wd = TE[row * 2 + 0], td = TE[row * 2 + 1];
  float v = W1[wd * ND + d] + W1[(7 + td) * ND + d] + b1[d];
  s[d] = v > 0.f ? v : 0.f;
  __syncthreads();
  float acc = b2[d];
  #pragma unroll 8
  for (int k = 0; k < ND; k++) acc = fmaf(s[k], W2[k * ND + d], acc);
  te[row * ND + d] = acc;
}

__global__ void k_zero(float* __restrict__ p, int n) {
  int i = blockIdx.x * 256 + threadIdx.x;
  if (i < n) p[i] = 0.f;
}

// Build CSR for S0/S1 (row-major gather: O[m] = sum_k S[m,k] V[k]).
// One wave per (row m, support z); ballot-compaction, deterministic order.
__global__ void k_csr(const float* __restrict__ S0g, const float* __restrict__ S1g,
                      int* __restrict__ cnt, int* __restrict__ idx,
                      float* __restrict__ val) {
  int m = blockIdx.x, z = blockIdx.y;
  const float* S = z ? S1g : S0g;
  int lane = threadIdx.x;
  int c = 0;
  for (int k0 = 0; k0 < NN; k0 += 64) {
    int k = k0 + lane;
    float v = (k < NN) ? S[m * NN + k] : 0.f;
    bool p = (v != 0.f);
    unsigned long long mask = __ballot(p);
    int pos = c + __popcll(mask & ((1ull << lane) - 1ull));
    if (p) {
      idx[(z * NN + m) * CAP + pos] = k;
      val[(z * NN + m) * CAP + pos] = v;
    }
    c += __popcll(mask);
  }
  if (lane == 0) cnt[z * NN + m] = c;
}

// Sparse S-matmul: O[m,:] = sum_j val[j] * Vin[idx[j],:].  C cols, 1024 per block.
template<int C>
__global__ void k_sspmm(const int* __restrict__ cnt, const int* __restrict__ idx,
                        const float* __restrict__ val, const float* __restrict__ Vin,
                        float* __restrict__ O0, float* __restrict__ O1) {
  int z = blockIdx.z;
  int m = blockIdx.y;
  int c = blockIdx.x * 1024 + threadIdx.x * 4;
  float* O = z ? O1 : O0;
  __shared__ int   sIdx[CAP];
  __shared__ float sVal[CAP];
  int n = cnt[z * NN + m];
  if ((int)threadIdx.x < n) {
    sIdx[threadIdx.x] = idx[(z * NN + m) * CAP + threadIdx.x];
    sVal[threadIdx.x] = val[(z * NN + m) * CAP + threadIdx.x];
  }
  __syncthreads();
  float4 acc = make_float4(0.f, 0.f, 0.f, 0.f);
  int j = 0;
  for (; j + 2 <= n; j += 2) {
    float a0 = sVal[j], a1 = sVal[j + 1];
    float4 v0 = *(const float4*)&Vin[(size_t)sIdx[j] * C + c];
    float4 v1 = *(const float4*)&Vin[(size_t)sIdx[j + 1] * C + c];
    acc.x = fmaf(a0, v0.x, acc.x); acc.y = fmaf(a0, v0.y, acc.y);
    acc.z = fmaf(a0, v0.z, acc.z); acc.w = fmaf(a0, v0.w, acc.w);
    acc.x = fmaf(a1, v1.x, acc.x); acc.y = fmaf(a1, v1.y, acc.y);
    acc.z = fmaf(a1, v1.z, acc.z); acc.w = fmaf(a1, v1.w, acc.w);
  }
  if (j < n) {
    float a0 = sVal[j];
    float4 v0 = *(const float4*)&Vin[(size_t)sIdx[j] * C + c];
    acc.x = fmaf(a0, v0.x, acc.x); acc.y = fmaf(a0, v0.y, acc.y);
    acc.z = fmaf(a0, v0.z, acc.z); acc.w = fmaf(a0, v0.w, acc.w);
  }
  *(float4*)&O[(size_t)m * C + c] = acc;
}

// Build V = [x_t | h] in layout (N, B, 128). Encoder: x_t = embX + te + E_se;
// decoder: x_t = te + E_se.
__global__ void k_buildV(const float* __restrict__ X, const float* __restrict__ te,
                         const float* __restrict__ E_se, const float* __restrict__ Wi1,
                         const float* __restrict__ bi1, const float* __restrict__ Wi2,
                         const float* __restrict__ bi2, const float* __restrict__ h,
                         float* __restrict__ V, int t, int is_enc) {
  int row = blockIdx.x;            // n*64 + b
  int n = row >> 6, b = row & 63;
  int d = threadIdx.x;
  __shared__ float s[ND];
  float acc;
  if (is_enc) {
    float x = X[(b * NP + t) * NN + n];
    float v = fmaf(x, Wi1[d], bi1[d]);
    s[d] = v > 0.f ? v : 0.f;
    __syncthreads();
    acc = bi2[d];
    #pragma unroll 8
    for (int k = 0; k < ND; k++) acc = fmaf(s[k], Wi2[k * ND + d], acc);
    acc += te[(b * NT + t) * ND + d] + E_se[n * ND + d];
  } else {
    acc = te[(b * NT + NP + t) * ND + d] + E_se[n * ND + d];
  }
  V[row * CF + d] = acc;
  V[row * CF + ND + d] = h[row * ND + d];
}

// (20800 x 384) @ W(384 x NW). A gathered from 6 K-chunks of 64 (ptr+stride each).
// MODE 0 (gate): val=sigmoid(acc+bg); c<64 -> rh = r*h ; c>=64 -> u.
// MODE 1 (cand): c=tanh(acc+bc); h = u*h + (1-u)*c  (in place).
template<int NW, int MODE>
__global__ void k_gemm(Chunks ch, const float* __restrict__ W,
                       const float* __restrict__ bias, float* hbuf,
                       float* rh, float* ubuf) {
  int row0 = blockIdx.y * 64;
  int c0 = blockIdx.x * 64;
  int tid = threadIdx.x;
  int tx = tid & 15, ty = tid >> 4;
  __shared__ float sA[64][20];   // padded; float4 stores stay 16B-aligned (20*4=80)
  __shared__ float sB[16][64];
  float acc[4][4] = {};
  for (int kt = 0; kt < 24; kt++) {        // 384 / 16
    int chunk = kt >> 2;
    int kin = (kt & 3) * 16;
    const float* Ap = ch.p[chunk];
    int As = ch.s[chunk];
    {
      int mm = tid >> 2;
      int kq = (tid & 3) * 4;
      *(float4*)&sA[mm][kq] = *(const float4*)(Ap + (size_t)(row0 + mm) * As + kin + kq);
    }
    {
      int kk = tid >> 4;
      int cq = (tid & 15) * 4;
      *(float4*)&sB[kk][cq] = *(const float4*)&W[(size_t)(kt * 16 + kk) * NW + c0 + cq];
    }
    __syncthreads();
    #pragma unroll
    for (int k = 0; k < 16; k++) {
      float4 bv = *(const float4*)&sB[k][tx * 4];
      #pragma unroll
      for (int j = 0; j < 4; j++) {
        float a = sA[ty * 4 + j][k];
        acc[j][0] = fmaf(a, bv.x, acc[j][0]);
        acc[j][1] = fmaf(a, bv.y, acc[j][1]);
        acc[j][2] = fmaf(a, bv.z, acc[j][2]);
        acc[j][3] = fmaf(a, bv.w, acc[j][3]);
      }
    }
    __syncthreads();
  }
  #pragma unroll
  for (int j = 0; j < 4; j++) {
    int row = row0 + ty * 4 + j;
    #pragma unroll
    for (int i = 0; i < 4; i++) {
      int c = c0 + tx * 4 + i;
      float v = acc[j][i] + bias[c];
      if (MODE == 0) {
        float sg = 1.f / (1.f + __expf(-v));
        if (c < ND) rh[row * ND + c] = sg * hbuf[row * ND + c];
        else        ubuf[row * ND + (c - ND)] = sg;
      } else {
        float cv = tanhf(v);
        float u = ubuf[row * ND + c];
        float hold = hbuf[row * ND + c];
        hbuf[row * ND + c] = u * hold + (1.f - u) * cv;
      }
    }
  }
}

// out[b,q,n] = relu(h[n,b,:] @ W1 + b1) @ W2 + b2
__global__ void k_out(const float* __restrict__ h, const float* __restrict__ W1,
                      const float* __restrict__ b1, const float* __restrict__ W2,
                      const float* __restrict__ b2, float* __restrict__ out, int q) {
  int row = blockIdx.x;            // n*64 + b
  int n = row >> 6, b = row & 63;
  int d = threadIdx.x;
  __shared__ float s[ND];
  s[d] = h[row * ND + d];
  __syncthreads();
  float acc = b1[d];
  #pragma unroll 8
  for (int k = 0; k < ND; k++) acc = fmaf(s[k], W1[k * ND + d], acc);
  acc = acc > 0.f ? acc : 0.f;
  float p = acc * W2[d];
  #pragma unroll
  for (int off = 32; off > 0; off >>= 1) p += __shfl_down(p, off);
  if (d == 0) out[(b * NQ + q) * NN + n] = p + b2[0];
}

extern "C" void kernel_launch(void* const* d_in, const int* in_sizes, int n_in,
                              void* d_out, int out_size, void* d_ws, size_t ws_size,
                              hipStream_t stream) {
  const float* X     = (const float*)d_in[0];
  const int*   TE    = (const int*)  d_in[1];
  const float* S0    = (const float*)d_in[2];
  const float* S1    = (const float*)d_in[3];
  const float* W_te1 = (const float*)d_in[4];
  const float* b_te1 = (const float*)d_in[5];
  const float* W_te2 = (const float*)d_in[6];
  const float* b_te2 = (const float*)d_in[7];
  const float* E_se  = (const float*)d_in[8];
  const float* W_in1 = (const float*)d_in[9];
  const float* b_in1 = (const float*)d_in[10];
  const float* W_in2 = (const float*)d_in[11];
  const float* b_in2 = (const float*)d_in[12];
  const float* enc_Wg = (const float*)d_in[13];
  const float* enc_bg = (const float*)d_in[14];
  const float* enc_Wc = (const float*)d_in[15];
  const float* enc_bc = (const float*)d_in[16];
  const float* dec_Wg = (const float*)d_in[17];
  const float* dec_bg = (const float*)d_in[18];
  const float* dec_Wc = (const float*)d_in[19];
  const float* dec_bc = (const float*)d_in[20];
  const float* W_out1 = (const float*)d_in[21];
  const float* b_out1 = (const float*)d_in[22];
  const float* W_out2 = (const float*)d_in[23];
  const float* b_out2 = (const float*)d_in[24];
  float* out = (float*)d_out;
  float* ws = (float*)d_ws;

  // workspace layout (floats)
  float* te   = ws;                 // 1536*64      =    98304
  float* h    = te   + 98304;       // NR*64        =  1331200
  float* V    = h    + 1331200;     // NR*128       =  2662400
  float* SV0  = V    + 2662400;
  float* SV1  = SV0  + 2662400;
  float* RH   = SV1  + 2662400;     // NR*64
  float* SRH0 = RH   + 1331200;
  float* SRH1 = SRH0 + 1331200;
  float* U    = SRH1 + 1331200;     // NR*64
  float* csrV = U    + 1331200;     // 2*NN*CAP = 41600
  int*   csrI = (int*)(csrV + 2 * NN * CAP);
  int*   csrC = csrI + 2 * NN * CAP;   // 650 ints; total ~59.3 MiB

  k_te<<<NB * NT, ND, 0, stream>>>(TE, W_te1, b_te1, W_te2, b_te2, te);
  k_zero<<<(1331200 + 255) / 256, 256, 0, stream>>>(h, 1331200);
  k_csr<<<dim3(NN, 2), 64, 0, stream>>>(S0, S1, csrC, csrI, csrV);

  Chunks gateCh{{V, V + ND, SV0, SV0 + ND, SV1, SV1 + ND}, {CF, CF, CF, CF, CF, CF}};
  Chunks candCh{{V, RH, SV0, SRH0, SV1, SRH1}, {CF, ND, CF, ND, CF, ND}};

  for (int t = 0; t < NT; t++) {
    int enc = (t < NP) ? 1 : 0;
    int tt = enc ? t : t - NP;
    const float* Wg = enc ? enc_Wg : dec_Wg;
    const float* bg = enc ? enc_bg : dec_bg;
    const float* Wc = enc ? enc_Wc : dec_Wc;
    const float* bc = enc ? enc_bc : dec_bc;

    k_buildV<<<NR, ND, 0, stream>>>(X, te, E_se, W_in1, b_in1, W_in2, b_in2, h, V, tt, enc);
    k_sspmm<CF * NB><<<dim3(8, NN, 2), 256, 0, stream>>>(csrC, csrI, csrV, V, SV0, SV1);
    k_gemm<128, 0><<<dim3(2, 325), 256, 0, stream>>>(gateCh, Wg, bg, h, RH, U);
    k_sspmm<ND * NB><<<dim3(4, NN, 2), 256, 0, stream>>>(csrC, csrI, csrV, RH, SRH0, SRH1);
    k_gemm<64, 1><<<dim3(1, 325), 256, 0, stream>>>(candCh, Wc, bc, h, RH, U);
    if (!enc) k_out<<<NR, ND, 0, stream>>>(h, W_out1, b_out1, W_out2, b_out2, out, tt);
  }
}

// Round 3
// 2475.706 us; speedup vs baseline: 1.8978x; 1.2065x over previous
//
#include <hip/hip_runtime.h>
#include <math.h>

#define NB 64      // batch
#define NP 12      // encoder steps
#define NQ 12      // decoder steps
#define NT 24      // P+Q
#define NN 325     // nodes
#define ND 64      // units
#define CF 128     // 2*D
#define NR 20800   // NN*NB rows
#define CAP 64     // max nnz per S row

typedef __attribute__((ext_vector_type(8))) short frag8;

struct Chunks { const float* p[6]; int s[6]; };

__device__ inline unsigned short f2bf(float f) {
  unsigned u = __builtin_bit_cast(unsigned, f);
  unsigned r = u + 0x7FFFu + ((u >> 16) & 1u);
  return (unsigned short)(r >> 16);
}
__device__ inline float bf2f(unsigned short h) {
  unsigned u = ((unsigned)h) << 16;
  return __builtin_bit_cast(float, u);
}

__global__ void k_te(const int* __restrict__ TE, const float* __restrict__ W1,
                     const float* __restrict__ b1, const float* __restrict__ W2,
                     const float* __restrict__ b2, float* __restrict__ te) {
  int row = blockIdx.x;            // b*24+t  (1536 rows)
  int d = threadIdx.x;
  __shared__ float s[ND];
  int wd = TE[row * 2 + 0], td = TE[row * 2 + 1];
  float v = W1[wd * ND + d] + W1[(7 + td) * ND + d] + b1[d];
  s[d] = v > 0.f ? v : 0.f;
  __syncthreads();
  float acc = b2[d];
  #pragma unroll 8
  for (int k = 0; k < ND; k++) acc = fmaf(s[k], W2[k * ND + d], acc);
  te[row * ND + d] = acc;
}

__global__ void k_zero(float* __restrict__ p, int n) {
  int i = blockIdx.x * 256 + threadIdx.x;
  if (i < n) p[i] = 0.f;
}

// W (384 x nw) fp32 -> k-major bf16 hi/lo: Wh/Wl[n*384 + k]
__global__ void k_convW(const float* __restrict__ W, unsigned short* __restrict__ Wh,
                        unsigned short* __restrict__ Wl, int nw) {
  int k = blockIdx.x;              // 384
  int n = threadIdx.x;             // nw
  float w = W[k * nw + n];
  unsigned short h = f2bf(w);
  Wh[n * 384 + k] = h;
  Wl[n * 384 + k] = f2bf(w - bf2f(h));
}

// CSR build for S0/S1; one wave per (row, support), ballot compaction.
__global__ void k_csr(const float* __restrict__ S0g, const float* __restrict__ S1g,
                      int* __restrict__ cnt, int* __restrict__ idx,
                      float* __restrict__ val) {
  int m = blockIdx.x, z = blockIdx.y;
  const float* S = z ? S1g : S0g;
  int lane = threadIdx.x;
  int c = 0;
  for (int k0 = 0; k0 < NN; k0 += 64) {
    int k = k0 + lane;
    float v = (k < NN) ? S[m * NN + k] : 0.f;
    bool p = (v != 0.f);
    unsigned long long mask = __ballot(p);
    int pos = c + __popcll(mask & ((1ull << lane) - 1ull));
    if (p) {
      idx[(z * NN + m) * CAP + pos] = k;
      val[(z * NN + m) * CAP + pos] = v;
    }
    c += __popcll(mask);
  }
  if (lane == 0) cnt[z * NN + m] = c;
}

// Sparse S-matmul: O[m,:] = sum_j val[j] * Vin[idx[j],:]
template<int C>
__global__ void k_sspmm(const int* __restrict__ cnt, const int* __restrict__ idx,
                        const float* __restrict__ val, const float* __restrict__ Vin,
                        float* __restrict__ O0, float* __restrict__ O1) {
  int z = blockIdx.z;
  int m = blockIdx.y;
  int c = blockIdx.x * 1024 + threadIdx.x * 4;
  float* O = z ? O1 : O0;
  __shared__ int   sIdx[CAP];
  __shared__ float sVal[CAP];
  int n = cnt[z * NN + m];
  if ((int)threadIdx.x < n) {
    sIdx[threadIdx.x] = idx[(z * NN + m) * CAP + threadIdx.x];
    sVal[threadIdx.x] = val[(z * NN + m) * CAP + threadIdx.x];
  }
  __syncthreads();
  float4 acc = make_float4(0.f, 0.f, 0.f, 0.f);
  int j = 0;
  for (; j + 2 <= n; j += 2) {
    float a0 = sVal[j], a1 = sVal[j + 1];
    float4 v0 = *(const float4*)&Vin[(size_t)sIdx[j] * C + c];
    float4 v1 = *(const float4*)&Vin[(size_t)sIdx[j + 1] * C + c];
    acc.x = fmaf(a0, v0.x, acc.x); acc.y = fmaf(a0, v0.y, acc.y);
    acc.z = fmaf(a0, v0.z, acc.z); acc.w = fmaf(a0, v0.w, acc.w);
    acc.x = fmaf(a1, v1.x, acc.x); acc.y = fmaf(a1, v1.y, acc.y);
    acc.z = fmaf(a1, v1.z, acc.z); acc.w = fmaf(a1, v1.w, acc.w);
  }
  if (j < n) {
    float a0 = sVal[j];
    float4 v0 = *(const float4*)&Vin[(size_t)sIdx[j] * C + c];
    acc.x = fmaf(a0, v0.x, acc.x); acc.y = fmaf(a0, v0.y, acc.y);
    acc.z = fmaf(a0, v0.z, acc.z); acc.w = fmaf(a0, v0.w, acc.w);
  }
  *(float4*)&O[(size_t)m * C + c] = acc;
}

// Build V = [x_t | h] in layout (N, B, 128).
__global__ void k_buildV(const float* __restrict__ X, const float* __restrict__ te,
                         const float* __restrict__ E_se, const float* __restrict__ Wi1,
                         const float* __restrict__ bi1, const float* __restrict__ Wi2,
                         const float* __restrict__ bi2, const float* __restrict__ h,
                         float* __restrict__ V, int t, int is_enc) {
  int row = blockIdx.x;            // n*64 + b
  int n = row >> 6, b = row & 63;
  int d = threadIdx.x;
  __shared__ float s[ND];
  float acc;
  if (is_enc) {
    float x = X[(b * NP + t) * NN + n];
    float v = fmaf(x, Wi1[d], bi1[d]);
    s[d] = v > 0.f ? v : 0.f;
    __syncthreads();
    acc = bi2[d];
    #pragma unroll 8
    for (int k = 0; k < ND; k++) acc = fmaf(s[k], Wi2[k * ND + d], acc);
    acc += te[(b * NT + t) * ND + d] + E_se[n * ND + d];
  } else {
    acc = te[(b * NT + NP + t) * ND + d] + E_se[n * ND + d];
  }
  V[row * CF + d] = acc;
  V[row * CF + ND + d] = h[row * ND + d];
}

// MFMA GEMM: (20800 x 384) @ W(384 x NW), bf16x3 split, fp32 accumulate.
// A gathered fp32 from 6 K-chunks (ptr+stride); W preconverted bf16 hi/lo k-major.
// Block: 64-row panel x NW cols, 4 waves, wave tile 32 x NW/2.
// MODE 0 (gate): sg=sigmoid(acc+b); c<64 -> rh=sg*h ; c>=64 -> u=sg.
// MODE 1 (cand): cv=tanh(acc+b); h = u*h + (1-u)*cv  (in place).
template<int NW, int MODE>
__global__ void __launch_bounds__(256, 4)
k_gemm(Chunks ch, const unsigned short* __restrict__ Wh,
       const unsigned short* __restrict__ Wl, const float* __restrict__ bias,
       float* __restrict__ hbuf, float* __restrict__ rh, float* __restrict__ ubuf) {
  constexpr int CT = NW / 32;            // col tiles per wave
  int row0 = blockIdx.x * 64;
  int tid = threadIdx.x;
  int lane = tid & 63, w = tid >> 6;
  int rbase = (w & 1) * 32;
  int cbase = (w >> 1) * (NW / 2);
  // stride 40 bf16 (80 B): 16B-aligned rows, <=2-way LDS bank aliasing (free)
  __shared__ unsigned short Ah[64 * 40], Al[64 * 40];
  __shared__ unsigned short Bh[NW * 40], Bl[NW * 40];
  using f32x4 = __attribute__((ext_vector_type(4))) float;
  f32x4 acc[2][CT];
  #pragma unroll
  for (int i = 0; i < 2; i++)
    #pragma unroll
    for (int j = 0; j < CT; j++) acc[i][j] = (f32x4)0.f;

  for (int kt = 0; kt < 12; kt++) {      // 12 slabs of K=32
    int chunk = kt >> 1, kin = (kt & 1) * 32;
    const float* Ap = ch.p[chunk];
    int As = ch.s[chunk];
    // stage A: 64 rows x 32 k, fp32 -> bf16 hi/lo
    #pragma unroll
    for (int p = 0; p < 2; p++) {
      int r = (tid >> 3) + p * 32;
      int kf = (tid & 7) * 4;
      float4 v = *(const float4*)(Ap + (size_t)(row0 + r) * As + kin + kf);
      unsigned short h0 = f2bf(v.x), h1 = f2bf(v.y), h2 = f2bf(v.z), h3 = f2bf(v.w);
      unsigned short l0 = f2bf(v.x - bf2f(h0)), l1 = f2bf(v.y - bf2f(h1));
      unsigned short l2 = f2bf(v.z - bf2f(h2)), l3 = f2bf(v.w - bf2f(h3));
      ushort4 hv = {h0, h1, h2, h3}, lv = {l0, l1, l2, l3};
      *(ushort4*)&Ah[r * 40 + kf] = hv;
      *(ushort4*)&Al[r * 40 + kf] = lv;
    }
    // stage B: NW rows x 32 k bf16 (straight copy, k-major source)
    #pragma unroll
    for (int i = tid; i < NW * 4; i += 256) {
      int n = i >> 2, q = (i & 3) * 8;
      *(frag8*)&Bh[n * 40 + q] = *(const frag8*)&Wh[n * 384 + kt * 32 + q];
      *(frag8*)&Bl[n * 40 + q] = *(const frag8*)&Wl[n * 384 + kt * 32 + q];
    }
    __syncthreads();
    int rq = (lane >> 4) * 8;
    frag8 fa_h[2], fa_l[2], fb_h[CT], fb_l[CT];
    #pragma unroll
    for (int rt = 0; rt < 2; rt++) {
      int r = rbase + rt * 16 + (lane & 15);
      fa_h[rt] = *(const frag8*)&Ah[r * 40 + rq];
      fa_l[rt] = *(const frag8*)&Al[r * 40 + rq];
    }
    #pragma unroll
    for (int ct = 0; ct < CT; ct++) {
      int c = cbase + ct * 16 + (lane & 15);
      fb_h[ct] = *(const frag8*)&Bh[c * 40 + rq];
      fb_l[ct] = *(const frag8*)&Bl[c * 40 + rq];
    }
    #pragma unroll
    for (int rt = 0; rt < 2; rt++)
      #pragma unroll
      for (int ct = 0; ct < CT; ct++) {
        acc[rt][ct] = __builtin_amdgcn_mfma_f32_16x16x32_bf16(fa_h[rt], fb_h[ct], acc[rt][ct], 0, 0, 0);
        acc[rt][ct] = __builtin_amdgcn_mfma_f32_16x16x32_bf16(fa_l[rt], fb_h[ct], acc[rt][ct], 0, 0, 0);
        acc[rt][ct] = __builtin_amdgcn_mfma_f32_16x16x32_bf16(fa_h[rt], fb_l[ct], acc[rt][ct], 0, 0, 0);
      }
    __syncthreads();
  }
  // epilogue: C/D layout col=lane&15, row=(lane>>4)*4+reg
  #pragma unroll
  for (int rt = 0; rt < 2; rt++)
    #pragma unroll
    for (int ct = 0; ct < CT; ct++)
      #pragma unroll
      for (int g = 0; g < 4; g++) {
        int r = row0 + rbase + rt * 16 + (lane >> 4) * 4 + g;
        int c = cbase + ct * 16 + (lane & 15);
        float v = acc[rt][ct][g] + bias[c];
        if (MODE == 0) {
          float sg = 1.f / (1.f + __expf(-v));
          if (NW == 128 && c >= ND) ubuf[r * ND + (c - ND)] = sg;
          else rh[r * ND + c] = sg * hbuf[r * ND + c];
        } else {
          float cv = tanhf(v);
          float u = ubuf[r * ND + c];
          float ho = hbuf[r * ND + c];
          hbuf[r * ND + c] = u * ho + (1.f - u) * cv;
        }
      }
}

// out[b,q,n] = relu(h[n,b,:] @ W1 + b1) @ W2 + b2
__global__ void k_out(const float* __restrict__ h, const float* __restrict__ W1,
                      const float* __restrict__ b1, const float* __restrict__ W2,
                      const float* __restrict__ b2, float* __restrict__ out, int q) {
  int row = blockIdx.x;            // n*64 + b
  int n = row >> 6, b = row & 63;
  int d = threadIdx.x;
  __shared__ float s[ND];
  s[d] = h[row * ND + d];
  __syncthreads();
  float acc = b1[d];
  #pragma unroll 8
  for (int k = 0; k < ND; k++) acc = fmaf(s[k], W1[k * ND + d], acc);
  acc = acc > 0.f ? acc : 0.f;
  float p = acc * W2[d];
  #pragma unroll
  for (int off = 32; off > 0; off >>= 1) p += __shfl_down(p, off);
  if (d == 0) out[(b * NQ + q) * NN + n] = p + b2[0];
}

extern "C" void kernel_launch(void* const* d_in, const int* in_sizes, int n_in,
                              void* d_out, int out_size, void* d_ws, size_t ws_size,
                              hipStream_t stream) {
  const float* X     = (const float*)d_in[0];
  const int*   TE    = (const int*)  d_in[1];
  const float* S0    = (const float*)d_in[2];
  const float* S1    = (const float*)d_in[3];
  const float* W_te1 = (const float*)d_in[4];
  const float* b_te1 = (const float*)d_in[5];
  const float* W_te2 = (const float*)d_in[6];
  const float* b_te2 = (const float*)d_in[7];
  const float* E_se  = (const float*)d_in[8];
  const float* W_in1 = (const float*)d_in[9];
  const float* b_in1 = (const float*)d_in[10];
  const float* W_in2 = (const float*)d_in[11];
  const float* b_in2 = (const float*)d_in[12];
  const float* enc_Wg = (const float*)d_in[13];
  const float* enc_bg = (const float*)d_in[14];
  const float* enc_Wc = (const float*)d_in[15];
  const float* enc_bc = (const float*)d_in[16];
  const float* dec_Wg = (const float*)d_in[17];
  const float* dec_bg = (const float*)d_in[18];
  const float* dec_Wc = (const float*)d_in[19];
  const float* dec_bc = (const float*)d_in[20];
  const float* W_out1 = (const float*)d_in[21];
  const float* b_out1 = (const float*)d_in[22];
  const float* W_out2 = (const float*)d_in[23];
  const float* b_out2 = (const float*)d_in[24];
  float* out = (float*)d_out;
  float* ws = (float*)d_ws;

  // workspace layout (floats)
  float* te   = ws;                 // 1536*64
  float* h    = te   + 98304;       // NR*64
  float* V    = h    + 1331200;     // NR*128
  float* SV0  = V    + 2662400;
  float* SV1  = SV0  + 2662400;
  float* RH   = SV1  + 2662400;     // NR*64
  float* SRH0 = RH   + 1331200;
  float* SRH1 = SRH0 + 1331200;
  float* U    = SRH1 + 1331200;     // NR*64
  float* csrV = U    + 1331200;     // 2*NN*CAP
  int*   csrI = (int*)(csrV + 2 * NN * CAP);
  int*   csrC = csrI + 2 * NN * CAP;
  // bf16 weight buffers (ushort), after csrC (650 ints, pad to 1024)
  unsigned short* wbuf = (unsigned short*)(csrC + 1024);
  unsigned short* egWh = wbuf;                    // 128*384 each
  unsigned short* egWl = egWh + 49152;
  unsigned short* dgWh = egWl + 49152;
  unsigned short* dgWl = dgWh + 49152;
  unsigned short* ecWh = dgWl + 49152;            // 64*384 each
  unsigned short* ecWl = ecWh + 24576;
  unsigned short* dcWh = ecWl + 24576;
  unsigned short* dcWl = dcWh + 24576;            // total ~60 MiB

  k_te<<<NB * NT, ND, 0, stream>>>(TE, W_te1, b_te1, W_te2, b_te2, te);
  k_zero<<<(1331200 + 255) / 256, 256, 0, stream>>>(h, 1331200);
  k_csr<<<dim3(NN, 2), 64, 0, stream>>>(S0, S1, csrC, csrI, csrV);
  k_convW<<<384, 128, 0, stream>>>(enc_Wg, egWh, egWl, 128);
  k_convW<<<384, 128, 0, stream>>>(dec_Wg, dgWh, dgWl, 128);
  k_convW<<<384,  64, 0, stream>>>(enc_Wc, ecWh, ecWl, 64);
  k_convW<<<384,  64, 0, stream>>>(dec_Wc, dcWh, dcWl, 64);

  Chunks gateCh{{V, V + ND, SV0, SV0 + ND, SV1, SV1 + ND}, {CF, CF, CF, CF, CF, CF}};
  Chunks candCh{{V, RH, SV0, SRH0, SV1, SRH1}, {CF, ND, CF, ND, CF, ND}};

  for (int t = 0; t < NT; t++) {
    int enc = (t < NP) ? 1 : 0;
    int tt = enc ? t : t - NP;
    const unsigned short* Wgh = enc ? egWh : dgWh;
    const unsigned short* Wgl = enc ? egWl : dgWl;
    const unsigned short* Wch = enc ? ecWh : dcWh;
    const unsigned short* Wcl = enc ? ecWl : dcWl;
    const float* bg = enc ? enc_bg : dec_bg;
    const float* bc = enc ? enc_bc : dec_bc;

    k_buildV<<<NR, ND, 0, stream>>>(X, te, E_se, W_in1, b_in1, W_in2, b_in2, h, V, tt, enc);
    k_sspmm<CF * NB><<<dim3(8, NN, 2), 256, 0, stream>>>(csrC, csrI, csrV, V, SV0, SV1);
    k_gemm<128, 0><<<325, 256, 0, stream>>>(gateCh, Wgh, Wgl, bg, h, RH, U);
    k_sspmm<ND * NB><<<dim3(4, NN, 2), 256, 0, stream>>>(csrC, csrI, csrV, RH, SRH0, SRH1);
    k_gemm<64, 1><<<325, 256, 0, stream>>>(candCh, Wch, Wcl, bc, h, RH, U);
    if (!enc) k_out<<<NR, ND, 0, stream>>>(h, W_out1, b_out1, W_out2, b_out2, out, tt);
  }
}